// Round 7
// baseline (1050.951 us; speedup 1.0000x reference)
//
#include <hip/hip_runtime.h>
#include <hip/hip_bf16.h>

#define NTOK 4096
#define DM   1024
#define DF   4096
#define ROWS_TOTAL 12288   // 4096 shared + 8192 routed (top-2)
#define BM 128
#define BN 128
#define BK 64
#define SCALE_F 0.8944271909999159f
// worst-case sum of m-tiles over 9 experts: 32 (shared) + 71 (routed) = 103
#define PMAX 103

typedef __attribute__((ext_vector_type(8))) short short8;
typedef __attribute__((ext_vector_type(4))) float floatx4;

// async global->LDS, 16B/lane; LDS dest = wave-uniform base + lane*16 (m97/m104)
#define GLD16(gp, lp) __builtin_amdgcn_global_load_lds( \
    (const __attribute__((address_space(1))) void*)(gp), \
    (__attribute__((address_space(3))) void*)(lp), 16, 0, 0)

__device__ __forceinline__ ushort f2bf(float f){
    __hip_bfloat16 h = __float2bfloat16(f);
    return *reinterpret_cast<ushort*>(&h);
}

// 0.5x(1+tanh(u)) == x * sigmoid(2u), exp-form: ~6 VALU vs ~50 for tanhf
__device__ __forceinline__ float gelu_tanh(float v){
    float u2 = -1.5957691216057308f * (v + 0.044715f * v * v * v);
    return v / (1.0f + __expf(u2));
}

// bf16 convert for x only (weights convert inside gemm staging now).
// 8 floats/thread: 2x float4 loads -> 1x 16B short8 store. 4096*1024/8 = 524288.
__global__ __launch_bounds__(256) void cvt_x(
    const float* __restrict__ x, ushort* __restrict__ xb)
{
    unsigned i = blockIdx.x * 256u + threadIdx.x;
    const float4* s4 = reinterpret_cast<const float4*>(x) + 2 * (size_t)i;
    float4 a = s4[0];
    float4 b = s4[1];
    short8 o;
    o[0] = (short)f2bf(a.x); o[1] = (short)f2bf(a.y);
    o[2] = (short)f2bf(a.z); o[3] = (short)f2bf(a.w);
    o[4] = (short)f2bf(b.x); o[5] = (short)f2bf(b.y);
    o[6] = (short)f2bf(b.z); o[7] = (short)f2bf(b.w);
    reinterpret_cast<short8*>(xb)[i] = o;
}

// one wave per token: fp32 logits -> softmax -> top2
__global__ __launch_bounds__(256) void router_kernel(
    const float* __restrict__ x, const float* __restrict__ wr,
    int* __restrict__ te, float* __restrict__ tg, int* __restrict__ tokarr)
{
    const int token = blockIdx.x * 4 + (threadIdx.x >> 6);
    const int lane  = threadIdx.x & 63;
    const float* xp = x + (size_t)token * DM;
    float s[8];
    #pragma unroll
    for (int e = 0; e < 8; e++) s[e] = 0.f;
    for (int d = lane; d < DM; d += 64){
        float xv = xp[d];
        #pragma unroll
        for (int e = 0; e < 8; e++) s[e] += xv * wr[e * DM + d];
    }
    #pragma unroll
    for (int e = 0; e < 8; e++){
        float v = s[e];
        #pragma unroll
        for (int off = 32; off > 0; off >>= 1) v += __shfl_down(v, off);
        s[e] = v;
    }
    if (lane == 0){
        float m = s[0];
        #pragma unroll
        for (int e = 1; e < 8; e++) m = fmaxf(m, s[e]);
        float p[8]; float sum = 0.f;
        #pragma unroll
        for (int e = 0; e < 8; e++){ p[e] = __expf(s[e] - m); sum += p[e]; }
        float inv = 1.f / sum;
        #pragma unroll
        for (int e = 0; e < 8; e++) p[e] *= inv;
        int i1 = 0; float p1 = p[0];
        #pragma unroll
        for (int e = 1; e < 8; e++) if (p[e] > p1){ p1 = p[e]; i1 = e; }
        int i2 = -1; float p2 = -1.f;
        #pragma unroll
        for (int e = 0; e < 8; e++) if (e != i1 && p[e] > p2){ p2 = p[e]; i2 = e; }
        te[token*2+0] = i1; te[token*2+1] = i2;
        tg[token*2+0] = p1; tg[token*2+1] = p2;
        tokarr[token] = token;      // shared-expert rows = identity
    }
}

// single 256-thread block: counts -> prefix/meta -> scatter routed rows.
// meta layout: [0..8]=counts, [16..24]=rowbase, [32..40]=mtiles
__global__ __launch_bounds__(256) void plan_kernel(
    const int* __restrict__ te, int* __restrict__ tokarr,
    int* __restrict__ rowof, int* __restrict__ meta)
{
    __shared__ int lc[9], lcur[9];
    const int t = threadIdx.x;
    if (t < 9) lc[t] = 0;
    __syncthreads();
    for (int j = t; j < NTOK*2; j += 256) atomicAdd(&lc[te[j]], 1);
    __syncthreads();
    if (t == 0){
        int off = NTOK;
        for (int e = 0; e < 8; e++){
            lcur[e]    = off;
            meta[e]    = lc[e];
            meta[16+e] = off;
            meta[32+e] = (lc[e] + BM - 1) / BM;
            off += lc[e];
        }
        meta[8]    = NTOK;      // shared expert
        meta[16+8] = 0;
        meta[32+8] = NTOK / BM;
    }
    __syncthreads();
    for (int j = t; j < NTOK*2; j += 256){
        int e = te[j];
        int p = atomicAdd(&lcur[e], 1);
        tokarr[p] = j >> 1;
        rowof[j]  = p;
    }
}

// MODE 0: H[row] = gelu(Xg @ W1_e^T + b1)   (N=4096=32 nt, K=1024) -> bf16 H
// MODE 1: Y[row] = H @ W2_e^T + b2          (N=1024= 8 nt, K=4096) -> fp32 Y
// A (bf16): global_load_lds staging, round-0 swizzle (zero conflicts).
// B (fp32 weights): reg-staged loads + in-register f2bf + swizzled ds_write —
// fuses the bf16 conversion into the GEMM, deleting cvt_all's W traffic.
// Double-buffered LDS, round-4 schedule: ds_read -> fence -> issue(A GLD16 +
// B loads) -> fence -> MFMA -> cvt+ds_write -> __syncthreads.
template<int MODE>
__global__ __launch_bounds__(256) void gemm_kernel(
    const ushort* __restrict__ Abase,
    const float* __restrict__ Wf, const float* __restrict__ Wsf,
    const float* __restrict__ brout, const float* __restrict__ bsh,
    const int* __restrict__ meta, const int* __restrict__ tokarr,
    ushort* __restrict__ Hout, float* __restrict__ Yout)
{
    const int xcd = blockIdx.x & 7;
    const int q   = blockIdx.x >> 3;
    const int NTG = (MODE == 0) ? 4 : 1;     // nt-columns per expert per XCD

    int e = -1, r = 0, a0 = 0;
    #pragma unroll
    for (int ee = 0; ee < 9; ee++){
        int w = NTG * meta[32 + ee];
        if (e < 0 && q < a0 + w){ e = ee; r = q - a0; }
        a0 += w;
    }
    if (e < 0) return;
    const int mt_e = meta[32 + e];
    int ntg, mti;
    if (MODE == 0){ ntg = r / mt_e; mti = r - ntg * mt_e; }
    else          { ntg = 0;        mti = r; }
    const int nt   = (MODE == 0) ? (xcd + 8 * ntg) : xcd;
    const int cnt  = meta[e];
    const int base = meta[16 + e];

    const int K = (MODE == 0) ? DM : DF;
    const int N = (MODE == 0) ? DF : DM;
    const float* Bf   = (e < 8) ? (Wf + (size_t)e * DF * DM) : Wsf;
    const float* bias = (e < 8) ? (brout + e * N) : bsh;

    __shared__ __align__(16) ushort As[2][BM * BK];  // 16 KB each
    __shared__ __align__(16) ushort Bs[2][BN * BK];  // 16 KB each (64 KB total)

    const int t    = threadIdx.x;
    const int lane = t & 63;
    const int wv   = t >> 6;
    const int wm   = (wv >> 1) * 64;
    const int wn   = (wv & 1) * 64;
    const int lrow = lane & 15;
    const int quad = lane >> 4;
    // A staging swizzle (16B units): phys_seg = log_seg ^ (row&7)  [round-0]
    const int swz8 = ((lane & 7) ^ (lane >> 3)) * 8;

    // A: 4 GLD16/thread/step, rows rin = wv*32 + i*8 + (lane>>3)
    const ushort* Ap[4];
    int Aoff[4];
    #pragma unroll
    for (int i = 0; i < 4; i++){
        int rin = wv * 32 + i * 8 + (lane >> 3);
        int pos = mti * BM + rin;
        int clp = (pos < cnt) ? pos : (cnt - 1);
        if (MODE == 0) Ap[i] = Abase + (size_t)tokarr[base + clp] * DM + swz8;
        else           Ap[i] = Abase + (size_t)(base + clp) * DF + swz8;
        Aoff[i] = (wv * 32 + i * 8) * BK;
    }

    // B: thread t owns row rB = t>>1, fp32 col-half h = t&1 (cols h*32..h*32+31).
    // Stores 4 b128 segs: logical seg = h*4+k, phys = seg ^ (rB&7)  (matches read).
    const int rB = t >> 1;
    const int h  = t & 1;
    const float* BpF = Bf + (size_t)(nt * BN + rB) * K + h * 32;
    int wrOff[4];
    #pragma unroll
    for (int k = 0; k < 4; k++)
        wrOff[k] = rB * BK + (((h * 4 + k) ^ (rB & 7)) * 8);

    floatx4 acc[4][4];
    #pragma unroll
    for (int mi = 0; mi < 4; mi++)
        #pragma unroll
        for (int ni = 0; ni < 4; ni++)
            acc[mi][ni] = (floatx4){0.f, 0.f, 0.f, 0.f};

    // ---- B helpers -------------------------------------------------------
    auto bload = [&](float4* br, int kg){
        const float4* src = reinterpret_cast<const float4*>(BpF + kg);
        #pragma unroll
        for (int j = 0; j < 8; j++) br[j] = src[j];
    };
    auto bstore = [&](const float4* br, ushort* BsN){
        #pragma unroll
        for (int k = 0; k < 4; k++){
            float4 u = br[2*k], v = br[2*k+1];
            short8 o;
            o[0] = (short)f2bf(u.x); o[1] = (short)f2bf(u.y);
            o[2] = (short)f2bf(u.z); o[3] = (short)f2bf(u.w);
            o[4] = (short)f2bf(v.x); o[5] = (short)f2bf(v.y);
            o[6] = (short)f2bf(v.z); o[7] = (short)f2bf(v.w);
            *reinterpret_cast<short8*>(&BsN[wrOff[k]]) = o;
        }
    };

    // one phase: consume buf cur; prefetch k-next into buf nxt.
    auto phase = [&](const ushort* AsC, const ushort* BsC,
                     ushort* AsN, ushort* BsN, int knext, bool pf){
        short8 af0[4], af1[4], bf0[4], bf1[4];
        #pragma unroll
        for (int mi = 0; mi < 4; mi++){
            int row = wm + mi * 16 + lrow;
            int p0  = (0 + quad) ^ (row & 7);
            int p1  = (4 + quad) ^ (row & 7);
            af0[mi] = *reinterpret_cast<const short8*>(&AsC[row * BK + p0 * 8]);
            af1[mi] = *reinterpret_cast<const short8*>(&AsC[row * BK + p1 * 8]);
        }
        #pragma unroll
        for (int ni = 0; ni < 4; ni++){
            int row = wn + ni * 16 + lrow;
            int p0  = (0 + quad) ^ (row & 7);
            int p1  = (4 + quad) ^ (row & 7);
            bf0[ni] = *reinterpret_cast<const short8*>(&BsC[row * BK + p0 * 8]);
            bf1[ni] = *reinterpret_cast<const short8*>(&BsC[row * BK + p1 * 8]);
        }
        __builtin_amdgcn_sched_barrier(0);   // loads issue after ds_reads
        float4 br[8];
        if (pf){
            #pragma unroll
            for (int i = 0; i < 4; i++) GLD16(Ap[i] + knext, AsN + Aoff[i]);
            bload(br, knext);
        }
        __builtin_amdgcn_sched_barrier(0);   // MFMAs after load issues
        #pragma unroll
        for (int mi = 0; mi < 4; mi++)
            #pragma unroll
            for (int ni = 0; ni < 4; ni++)
                acc[mi][ni] = __builtin_amdgcn_mfma_f32_16x16x32_bf16(af0[mi], bf0[ni], acc[mi][ni], 0, 0, 0);
        #pragma unroll
        for (int mi = 0; mi < 4; mi++)
            #pragma unroll
            for (int ni = 0; ni < 4; ni++)
                acc[mi][ni] = __builtin_amdgcn_mfma_f32_16x16x32_bf16(af1[mi], bf1[ni], acc[mi][ni], 0, 0, 0);
        if (pf) bstore(br, BsN);             // compiler waits vmcnt for br here
        __syncthreads();                     // drains vm (A GLD16) + lgkm (B writes)
    };

    // prologue: stage tile 0 -> buf0
    {
        #pragma unroll
        for (int i = 0; i < 4; i++) GLD16(Ap[i], &As[0][Aoff[i]]);
        float4 br[8];
        bload(br, 0);
        bstore(br, Bs[0]);
        __syncthreads();
    }

    // main loop, 2 K-tiles per iteration (K/BK = 16 or 64, even)
    #pragma unroll 1
    for (int k0 = 0; k0 < K; k0 += 2 * BK){
        phase(As[0], Bs[0], As[1], Bs[1], k0 + BK,     true);
        phase(As[1], Bs[1], As[0], Bs[0], k0 + 2 * BK, k0 + 2 * BK < K);
    }

    // epilogue; C/D: col = lane&15, row = quad*4 + reg  [m89]
    float bv[4];
    #pragma unroll
    for (int ni = 0; ni < 4; ni++) bv[ni] = bias[nt * BN + wn + ni*16 + lrow];

    #pragma unroll
    for (int mi = 0; mi < 4; mi++){
        #pragma unroll
        for (int rg = 0; rg < 4; rg++){
            int s   = wm + mi*16 + quad*4 + rg;
            int pos = mti * BM + s;
            if (pos >= cnt) continue;
            int rr = base + pos;
            if (MODE == 0){
                ushort* hp = Hout + (size_t)rr * DF + nt * BN;
                #pragma unroll
                for (int ni = 0; ni < 4; ni++){
                    float v = acc[mi][ni][rg] + bv[ni];
                    hp[wn + ni*16 + lrow] = f2bf(gelu_tanh(v));
                }
            } else {
                float* yp = Yout + (size_t)rr * DM + nt * BN;
                #pragma unroll
                for (int ni = 0; ni < 4; ni++)
                    yp[wn + ni*16 + lrow] = acc[mi][ni][rg] + bv[ni];
            }
        }
    }
}

// out[t] = SCALE * (Y[t] + g1*Y[r1] + g2*Y[r2])
__global__ __launch_bounds__(256) void combine_kernel(
    const float* __restrict__ Y, const int* __restrict__ rowof,
    const float* __restrict__ tg, float* __restrict__ out)
{
    const int token = blockIdx.x;
    const int d4    = threadIdx.x;
    const float4* Y4 = reinterpret_cast<const float4*>(Y);
    int r1 = rowof[token*2+0], r2 = rowof[token*2+1];
    float g1 = tg[token*2+0],  g2 = tg[token*2+1];
    float4 a = Y4[(size_t)token * 256 + d4];
    float4 b = Y4[(size_t)r1 * 256 + d4];
    float4 c = Y4[(size_t)r2 * 256 + d4];
    float4 o;
    o.x = SCALE_F * (a.x + g1*b.x + g2*c.x);
    o.y = SCALE_F * (a.y + g1*b.y + g2*c.y);
    o.z = SCALE_F * (a.z + g1*b.z + g2*c.z);
    o.w = SCALE_F * (a.w + g1*b.w + g2*c.w);
    reinterpret_cast<float4*>(out)[(size_t)token * 256 + d4] = o;
}

extern "C" void kernel_launch(void* const* d_in, const int* in_sizes, int n_in,
                              void* d_out, int out_size, void* d_ws, size_t ws_size,
                              hipStream_t stream) {
    const float* x   = (const float*)d_in[0];
    const float* wr  = (const float*)d_in[1];
    const float* W1  = (const float*)d_in[2];
    const float* b1  = (const float*)d_in[3];
    const float* W2  = (const float*)d_in[4];
    const float* b2  = (const float*)d_in[5];
    const float* Ws1 = (const float*)d_in[6];
    const float* bs1 = (const float*)d_in[7];
    const float* Ws2 = (const float*)d_in[8];
    const float* bs2 = (const float*)d_in[9];
    float* out = (float*)d_out;

    char* ws = (char*)d_ws;
    size_t off = 0;
    auto wsalloc = [&](size_t bytes) -> char* {
        char* p = ws + off;
        off += (bytes + 255) & ~(size_t)255;
        return p;
    };
    ushort* xb   = (ushort*)wsalloc((size_t)NTOK * DM * 2);        //  8 MB
    ushort* H    = (ushort*)wsalloc((size_t)ROWS_TOTAL * DF * 2);  // 96 MB
    float*  Y    = (float*) wsalloc((size_t)ROWS_TOTAL * DM * 4);  // 50 MB
    int*    tokarr = (int*)wsalloc(ROWS_TOTAL * 4);
    int*    rowof  = (int*)wsalloc(NTOK * 2 * 4);
    int*    te     = (int*)wsalloc(NTOK * 2 * 4);
    float*  tg     = (float*)wsalloc(NTOK * 2 * 4);
    int*    meta   = (int*)wsalloc(64 * 4);

    cvt_x<<<2048, 256, 0, stream>>>(x, xb);
    router_kernel<<<NTOK/4, 256, 0, stream>>>(x, wr, te, tg, tokarr);
    plan_kernel<<<1, 256, 0, stream>>>(te, tokarr, rowof, meta);

    // grid = 8 XCD lanes x worst-case per-XCD queue length
    gemm_kernel<0><<<8 * 4 * PMAX, 256, 0, stream>>>(xb, W1, Ws1, b1, bs1,
        meta, tokarr, H, Y);
    gemm_kernel<1><<<8 * PMAX, 256, 0, stream>>>(H, W2, Ws2, b2, bs2,
        meta, tokarr, H, Y);

    combine_kernel<<<NTOK, 256, 0, stream>>>(Y, rowof, tg, out);
}

// Round 8
// 911.466 us; speedup vs baseline: 1.1530x; 1.1530x over previous
//
#include <hip/hip_runtime.h>
#include <hip/hip_bf16.h>

#define NTOK 4096
#define DM   1024
#define DF   4096
#define ROWS_TOTAL 12288   // 4096 shared + 8192 routed (top-2)
#define BM 128
#define BN 128
#define BK 64
#define SCALE_F 0.8944271909999159f
// worst-case sum of m-tiles over 9 experts: 32 (shared) + 71 (routed) = 103
#define PMAX 103

typedef __attribute__((ext_vector_type(8))) short short8;
typedef __attribute__((ext_vector_type(4))) float floatx4;

// async global->LDS, 16B/lane; LDS dest = wave-uniform base + lane*16 (m97/m104)
#define GLD16(gp, lp) __builtin_amdgcn_global_load_lds( \
    (const __attribute__((address_space(1))) void*)(gp), \
    (__attribute__((address_space(3))) void*)(lp), 16, 0, 0)

__device__ __forceinline__ ushort f2bf(float f){
    __hip_bfloat16 h = __float2bfloat16(f);
    return *reinterpret_cast<ushort*>(&h);
}

// 0.5x(1+tanh(u)) == x * sigmoid(2u), exp-form: ~6 VALU vs ~50 for tanhf
__device__ __forceinline__ float gelu_tanh(float v){
    float u2 = -1.5957691216057308f * (v + 0.044715f * v * v * v);
    return v / (1.0f + __expf(u2));
}

// bf16 convert for x only (weights convert inside gemm staging).
// 8 floats/thread: 2x float4 loads -> 1x 16B short8 store. 4096*1024/8 = 524288.
__global__ __launch_bounds__(256) void cvt_x(
    const float* __restrict__ x, ushort* __restrict__ xb)
{
    unsigned i = blockIdx.x * 256u + threadIdx.x;
    const float4* s4 = reinterpret_cast<const float4*>(x) + 2 * (size_t)i;
    float4 a = s4[0];
    float4 b = s4[1];
    short8 o;
    o[0] = (short)f2bf(a.x); o[1] = (short)f2bf(a.y);
    o[2] = (short)f2bf(a.z); o[3] = (short)f2bf(a.w);
    o[4] = (short)f2bf(b.x); o[5] = (short)f2bf(b.y);
    o[6] = (short)f2bf(b.z); o[7] = (short)f2bf(b.w);
    reinterpret_cast<short8*>(xb)[i] = o;
}

// one wave per token: fp32 logits -> softmax -> top2
__global__ __launch_bounds__(256) void router_kernel(
    const float* __restrict__ x, const float* __restrict__ wr,
    int* __restrict__ te, float* __restrict__ tg, int* __restrict__ tokarr)
{
    const int token = blockIdx.x * 4 + (threadIdx.x >> 6);
    const int lane  = threadIdx.x & 63;
    const float* xp = x + (size_t)token * DM;
    float s[8];
    #pragma unroll
    for (int e = 0; e < 8; e++) s[e] = 0.f;
    for (int d = lane; d < DM; d += 64){
        float xv = xp[d];
        #pragma unroll
        for (int e = 0; e < 8; e++) s[e] += xv * wr[e * DM + d];
    }
    #pragma unroll
    for (int e = 0; e < 8; e++){
        float v = s[e];
        #pragma unroll
        for (int off = 32; off > 0; off >>= 1) v += __shfl_down(v, off);
        s[e] = v;
    }
    if (lane == 0){
        float m = s[0];
        #pragma unroll
        for (int e = 1; e < 8; e++) m = fmaxf(m, s[e]);
        float p[8]; float sum = 0.f;
        #pragma unroll
        for (int e = 0; e < 8; e++){ p[e] = __expf(s[e] - m); sum += p[e]; }
        float inv = 1.f / sum;
        #pragma unroll
        for (int e = 0; e < 8; e++) p[e] *= inv;
        int i1 = 0; float p1 = p[0];
        #pragma unroll
        for (int e = 1; e < 8; e++) if (p[e] > p1){ p1 = p[e]; i1 = e; }
        int i2 = -1; float p2 = -1.f;
        #pragma unroll
        for (int e = 0; e < 8; e++) if (e != i1 && p[e] > p2){ p2 = p[e]; i2 = e; }
        te[token*2+0] = i1; te[token*2+1] = i2;
        tg[token*2+0] = p1; tg[token*2+1] = p2;
        tokarr[token] = token;      // shared-expert rows = identity
    }
}

// single 256-thread block: counts -> prefix/meta -> scatter routed rows.
// meta layout: [0..8]=counts, [16..24]=rowbase, [32..40]=mtiles
__global__ __launch_bounds__(256) void plan_kernel(
    const int* __restrict__ te, int* __restrict__ tokarr,
    int* __restrict__ rowof, int* __restrict__ meta)
{
    __shared__ int lc[9], lcur[9];
    const int t = threadIdx.x;
    if (t < 9) lc[t] = 0;
    __syncthreads();
    for (int j = t; j < NTOK*2; j += 256) atomicAdd(&lc[te[j]], 1);
    __syncthreads();
    if (t == 0){
        int off = NTOK;
        for (int e = 0; e < 8; e++){
            lcur[e]    = off;
            meta[e]    = lc[e];
            meta[16+e] = off;
            meta[32+e] = (lc[e] + BM - 1) / BM;
            off += lc[e];
        }
        meta[8]    = NTOK;      // shared expert
        meta[16+8] = 0;
        meta[32+8] = NTOK / BM;
    }
    __syncthreads();
    for (int j = t; j < NTOK*2; j += 256){
        int e = te[j];
        int p = atomicAdd(&lcur[e], 1);
        tokarr[p] = j >> 1;
        rowof[j]  = p;
    }
}

// MODE 0: H[row] = gelu(Xg @ W1_e^T + b1)   (N=4096=32 nt, K=1024) -> bf16 H
// MODE 1: Y[row] = H @ W2_e^T + b2          (N=1024= 8 nt, K=4096) -> fp32 Y
// A (bf16): global_load_lds, 2-buffer. B (fp32 weights): reg-staged with a
// FULL-PHASE flight window (round-7 fix): entering the phase that consumes
// tile k, br already holds tile k+1 (loaded during phase k-1). bstore's vmcnt
// wait therefore covers loads issued one whole phase earlier — the serial
// stall that collapsed round 7 (VALUBusy 7.6%) is gone.
template<int MODE>
__global__ __launch_bounds__(256) void gemm_kernel(
    const ushort* __restrict__ Abase,
    const float* __restrict__ Wf, const float* __restrict__ Wsf,
    const float* __restrict__ brout, const float* __restrict__ bsh,
    const int* __restrict__ meta, const int* __restrict__ tokarr,
    ushort* __restrict__ Hout, float* __restrict__ Yout)
{
    const int xcd = blockIdx.x & 7;
    const int q   = blockIdx.x >> 3;
    const int NTG = (MODE == 0) ? 4 : 1;     // nt-columns per expert per XCD

    int e = -1, r = 0, a0 = 0;
    #pragma unroll
    for (int ee = 0; ee < 9; ee++){
        int w = NTG * meta[32 + ee];
        if (e < 0 && q < a0 + w){ e = ee; r = q - a0; }
        a0 += w;
    }
    if (e < 0) return;
    const int mt_e = meta[32 + e];
    int ntg, mti;
    if (MODE == 0){ ntg = r / mt_e; mti = r - ntg * mt_e; }
    else          { ntg = 0;        mti = r; }
    const int nt   = (MODE == 0) ? (xcd + 8 * ntg) : xcd;
    const int cnt  = meta[e];
    const int base = meta[16 + e];

    const int K = (MODE == 0) ? DM : DF;
    const int N = (MODE == 0) ? DF : DM;
    const float* Bf   = (e < 8) ? (Wf + (size_t)e * DF * DM) : Wsf;
    const float* bias = (e < 8) ? (brout + e * N) : bsh;

    __shared__ __align__(16) ushort As[2][BM * BK];  // 16 KB each
    __shared__ __align__(16) ushort Bs[2][BN * BK];  // 16 KB each (64 KB total)

    const int t    = threadIdx.x;
    const int lane = t & 63;
    const int wv   = t >> 6;
    const int wm   = (wv >> 1) * 64;
    const int wn   = (wv & 1) * 64;
    const int lrow = lane & 15;
    const int quad = lane >> 4;
    // A staging swizzle (16B units): phys_seg = log_seg ^ (row&7)  [round-0]
    const int swz8 = ((lane & 7) ^ (lane >> 3)) * 8;

    // A: 4 GLD16/thread/step, rows rin = wv*32 + i*8 + (lane>>3)
    const ushort* Ap[4];
    int Aoff[4];
    #pragma unroll
    for (int i = 0; i < 4; i++){
        int rin = wv * 32 + i * 8 + (lane >> 3);
        int pos = mti * BM + rin;
        int clp = (pos < cnt) ? pos : (cnt - 1);
        if (MODE == 0) Ap[i] = Abase + (size_t)tokarr[base + clp] * DM + swz8;
        else           Ap[i] = Abase + (size_t)(base + clp) * DF + swz8;
        Aoff[i] = (wv * 32 + i * 8) * BK;
    }

    // B: thread t owns row rB = t>>1, fp32 col-half h = t&1 (cols h*32..h*32+31).
    // Stores 4 b128 segs: logical seg = h*4+k, phys = seg ^ (rB&7)  (matches read).
    const int rB = t >> 1;
    const int h  = t & 1;
    const float* BpF = Bf + (size_t)(nt * BN + rB) * K + h * 32;
    int wrOff[4];
    #pragma unroll
    for (int k = 0; k < 4; k++)
        wrOff[k] = rB * BK + (((h * 4 + k) ^ (rB & 7)) * 8);

    floatx4 acc[4][4];
    #pragma unroll
    for (int mi = 0; mi < 4; mi++)
        #pragma unroll
        for (int ni = 0; ni < 4; ni++)
            acc[mi][ni] = (floatx4){0.f, 0.f, 0.f, 0.f};

    float4 br[8];   // B reg-stage: holds the NEXT tile's fp32 strip (32 VGPR)

    auto bload = [&](int kg){
        const float4* src = reinterpret_cast<const float4*>(BpF + kg);
        #pragma unroll
        for (int j = 0; j < 8; j++) br[j] = src[j];
    };
    auto bstore = [&](ushort* BsN){
        #pragma unroll
        for (int k = 0; k < 4; k++){
            float4 u = br[2*k], v = br[2*k+1];
            short8 o;
            o[0] = (short)f2bf(u.x); o[1] = (short)f2bf(u.y);
            o[2] = (short)f2bf(u.z); o[3] = (short)f2bf(u.w);
            o[4] = (short)f2bf(v.x); o[5] = (short)f2bf(v.y);
            o[6] = (short)f2bf(v.z); o[7] = (short)f2bf(v.w);
            *reinterpret_cast<short8*>(&BsN[wrOff[k]]) = o;
        }
    };

    // phase: consume (AsC,BsC)=tile kA-BK; issue A(kA); MFMA; store br
    // (=tile kA, loaded LAST phase) into BsN; load br <- tile kB.
    auto phase = [&](const ushort* AsC, const ushort* BsC,
                     ushort* AsN, ushort* BsN, int kA, int kB){
        short8 af0[4], af1[4], bf0[4], bf1[4];
        #pragma unroll
        for (int mi = 0; mi < 4; mi++){
            int row = wm + mi * 16 + lrow;
            int p0  = (0 + quad) ^ (row & 7);
            int p1  = (4 + quad) ^ (row & 7);
            af0[mi] = *reinterpret_cast<const short8*>(&AsC[row * BK + p0 * 8]);
            af1[mi] = *reinterpret_cast<const short8*>(&AsC[row * BK + p1 * 8]);
        }
        #pragma unroll
        for (int ni = 0; ni < 4; ni++){
            int row = wn + ni * 16 + lrow;
            int p0  = (0 + quad) ^ (row & 7);
            int p1  = (4 + quad) ^ (row & 7);
            bf0[ni] = *reinterpret_cast<const short8*>(&BsC[row * BK + p0 * 8]);
            bf1[ni] = *reinterpret_cast<const short8*>(&BsC[row * BK + p1 * 8]);
        }
        __builtin_amdgcn_sched_barrier(0);   // A issues after ds_reads
        if (kA < K){
            #pragma unroll
            for (int i = 0; i < 4; i++) GLD16(Ap[i] + kA, AsN + Aoff[i]);
        }
        __builtin_amdgcn_sched_barrier(0);   // MFMAs after A issues
        #pragma unroll
        for (int mi = 0; mi < 4; mi++)
            #pragma unroll
            for (int ni = 0; ni < 4; ni++)
                acc[mi][ni] = __builtin_amdgcn_mfma_f32_16x16x32_bf16(af0[mi], bf0[ni], acc[mi][ni], 0, 0, 0);
        #pragma unroll
        for (int mi = 0; mi < 4; mi++)
            #pragma unroll
            for (int ni = 0; ni < 4; ni++)
                acc[mi][ni] = __builtin_amdgcn_mfma_f32_16x16x32_bf16(af1[mi], bf1[ni], acc[mi][ni], 0, 0, 0);
        __builtin_amdgcn_sched_barrier(0);   // br wait lands after MFMA cluster
        if (kA < K) bstore(BsN);             // waits loads issued LAST phase
        if (kB < K) bload(kB);               // issue tile kB (no wait)
        __syncthreads();
    };

    // prologue: B tile0 -> regs -> Bs[0] (one serial wait, once); A tile0 ->
    // As[0]; issue B tile1 so phase 0's bstore has a full-phase-old load.
    bload(0);
    #pragma unroll
    for (int i = 0; i < 4; i++) GLD16(Ap[i], &As[0][Aoff[i]]);
    bstore(Bs[0]);
    bload(BK);           // K >= 2*BK always (K = 1024 or 4096)
    __syncthreads();

    // main loop, 2 phases per iteration (K/BK = 16 or 64, even)
    #pragma unroll 1
    for (int k0 = 0; k0 < K; k0 += 2 * BK){
        phase(As[0], Bs[0], As[1], Bs[1], k0 + BK,     k0 + 2 * BK);
        phase(As[1], Bs[1], As[0], Bs[0], k0 + 2 * BK, k0 + 3 * BK);
    }

    // epilogue; C/D: col = lane&15, row = quad*4 + reg  [m89]
    float bv[4];
    #pragma unroll
    for (int ni = 0; ni < 4; ni++) bv[ni] = bias[nt * BN + wn + ni*16 + lrow];

    #pragma unroll
    for (int mi = 0; mi < 4; mi++){
        #pragma unroll
        for (int rg = 0; rg < 4; rg++){
            int s   = wm + mi*16 + quad*4 + rg;
            int pos = mti * BM + s;
            if (pos >= cnt) continue;
            int rr = base + pos;
            if (MODE == 0){
                ushort* hp = Hout + (size_t)rr * DF + nt * BN;
                #pragma unroll
                for (int ni = 0; ni < 4; ni++){
                    float v = acc[mi][ni][rg] + bv[ni];
                    hp[wn + ni*16 + lrow] = f2bf(gelu_tanh(v));
                }
            } else {
                float* yp = Yout + (size_t)rr * DM + nt * BN;
                #pragma unroll
                for (int ni = 0; ni < 4; ni++)
                    yp[wn + ni*16 + lrow] = acc[mi][ni][rg] + bv[ni];
            }
        }
    }
}

// out[t] = SCALE * (Y[t] + g1*Y[r1] + g2*Y[r2])
__global__ __launch_bounds__(256) void combine_kernel(
    const float* __restrict__ Y, const int* __restrict__ rowof,
    const float* __restrict__ tg, float* __restrict__ out)
{
    const int token = blockIdx.x;
    const int d4    = threadIdx.x;
    const float4* Y4 = reinterpret_cast<const float4*>(Y);
    int r1 = rowof[token*2+0], r2 = rowof[token*2+1];
    float g1 = tg[token*2+0],  g2 = tg[token*2+1];
    float4 a = Y4[(size_t)token * 256 + d4];
    float4 b = Y4[(size_t)r1 * 256 + d4];
    float4 c = Y4[(size_t)r2 * 256 + d4];
    float4 o;
    o.x = SCALE_F * (a.x + g1*b.x + g2*c.x);
    o.y = SCALE_F * (a.y + g1*b.y + g2*c.y);
    o.z = SCALE_F * (a.z + g1*b.z + g2*c.z);
    o.w = SCALE_F * (a.w + g1*b.w + g2*c.w);
    reinterpret_cast<float4*>(out)[(size_t)token * 256 + d4] = o;
}

extern "C" void kernel_launch(void* const* d_in, const int* in_sizes, int n_in,
                              void* d_out, int out_size, void* d_ws, size_t ws_size,
                              hipStream_t stream) {
    const float* x   = (const float*)d_in[0];
    const float* wr  = (const float*)d_in[1];
    const float* W1  = (const float*)d_in[2];
    const float* b1  = (const float*)d_in[3];
    const float* W2  = (const float*)d_in[4];
    const float* b2  = (const float*)d_in[5];
    const float* Ws1 = (const float*)d_in[6];
    const float* bs1 = (const float*)d_in[7];
    const float* Ws2 = (const float*)d_in[8];
    const float* bs2 = (const float*)d_in[9];
    float* out = (float*)d_out;

    char* ws = (char*)d_ws;
    size_t off = 0;
    auto wsalloc = [&](size_t bytes) -> char* {
        char* p = ws + off;
        off += (bytes + 255) & ~(size_t)255;
        return p;
    };
    ushort* xb   = (ushort*)wsalloc((size_t)NTOK * DM * 2);        //  8 MB
    ushort* H    = (ushort*)wsalloc((size_t)ROWS_TOTAL * DF * 2);  // 96 MB
    float*  Y    = (float*) wsalloc((size_t)ROWS_TOTAL * DM * 4);  // 50 MB
    int*    tokarr = (int*)wsalloc(ROWS_TOTAL * 4);
    int*    rowof  = (int*)wsalloc(NTOK * 2 * 4);
    int*    te     = (int*)wsalloc(NTOK * 2 * 4);
    float*  tg     = (float*)wsalloc(NTOK * 2 * 4);
    int*    meta   = (int*)wsalloc(64 * 4);

    cvt_x<<<2048, 256, 0, stream>>>(x, xb);
    router_kernel<<<NTOK/4, 256, 0, stream>>>(x, wr, te, tg, tokarr);
    plan_kernel<<<1, 256, 0, stream>>>(te, tokarr, rowof, meta);

    // grid = 8 XCD lanes x worst-case per-XCD queue length
    gemm_kernel<0><<<8 * 4 * PMAX, 256, 0, stream>>>(xb, W1, Ws1, b1, bs1,
        meta, tokarr, H, Y);
    gemm_kernel<1><<<8 * PMAX, 256, 0, stream>>>(H, W2, Ws2, b2, bs2,
        meta, tokarr, H, Y);

    combine_kernel<<<NTOK, 256, 0, stream>>>(Y, rowof, tg, out);
}